// Round 7
// baseline (172.711 us; speedup 1.0000x reference)
//
#include <hip/hip_runtime.h>
#include <stdint.h>

// ---------------------------------------------------------------------------
// BNNLinear: out = BatchNorm( sign(x) @ sign(W)^T )
//   x: [M, K] f32, W: [N, K] f32, gamma/beta: [N] f32  ->  out: [M, N] f32
//
// Round 13 (on round 12's 256^2 4-phase kernel, 50.0us, total 165us):
//   R12 post-mortem: partial win (57->50) but MfmaUtil 24.5% vs template's
//   62%. Root cause per m218 A/B (counted-vmcnt vs drain0 = +38-73%): my
//   tile boundary was __syncthreads = vmcnt(0)+lgkmcnt(0) full drain, with
//   the last prefetch issued only ~1 phase earlier -> true just-in-time
//   drain on the critical path.
//   This round = proper T4 counted pipeline, 2 tiles in flight:
//   - ALL staging moved to the tile boundary: after tile u-1's last phase
//     barrier (its buffer reads provably retired), issue all 8 loads for
//     tile u+1 into the freed buffer.
//   - Boundary wait = s_waitcnt vmcnt(8): waits only tile u's 8 loads
//     (issued 4 phases ~ 2800cyc ago >> 900cyc HBM), keeps tile u+1's 8
//     in flight across every barrier of tile u. vmcnt retires oldest-first
//     (m135). Raw s_barrier (no lgkm drain); sched_barrier(0) hygiene.
//   - Phases: pure {ds_read frags -> barrier -> setprio MFMA x16 -> barrier}.
//   Stats + per-panel no-fence spin barrier + in-reg BN epilogue unchanged
//   (R11-proven). XOR swizzle unchanged (0 bank conflicts).
// ---------------------------------------------------------------------------

typedef int int32x4 __attribute__((ext_vector_type(4)));

#define BM 256
#define BN 256
#define BKI 128  // i8 k-bytes per LDS tile
#define EPS_BN 1e-5f
#define BAR_STRIDE 32  // ints between panel counters (128B, no false sharing)

__device__ __forceinline__ void load16_lds(const void* g, void* l) {
  // 16B per lane, LDS dest = wave-uniform base + lane*16 (linear, no scatter)
  __builtin_amdgcn_global_load_lds(
      (const __attribute__((address_space(1))) void*)g,
      (__attribute__((address_space(3))) void*)l,
      16, 0, 0);
}

__device__ __forceinline__ char sgn(float v) {
  return v > 0.f ? (char)1 : (v < 0.f ? (char)-1 : (char)0);
}

// ---- 1) binarize f32 -> i8 sign (both tensors) + zero stats+barriers ------
__global__ void binarize_kernel(const float* __restrict__ x,
                                const float* __restrict__ w,
                                char* __restrict__ Ab, char* __restrict__ Bb,
                                float* __restrict__ stats,  // colSum|colSq|bar
                                int nx4, int ntot4, int n2) {
  int idx = blockIdx.x * blockDim.x + threadIdx.x;
  if (idx < n2) stats[idx] = 0.f;  // 0.0f bit pattern == int 0
  if (idx >= ntot4) return;
  const float4* src;
  char* dst;
  int i;
  if (idx < nx4) {
    src = reinterpret_cast<const float4*>(x); dst = Ab; i = idx;
  } else {
    src = reinterpret_cast<const float4*>(w); dst = Bb; i = idx - nx4;
  }
  float4 v = src[i];
  char4 o;
  o.x = sgn(v.x); o.y = sgn(v.y); o.z = sgn(v.z); o.w = sgn(v.w);
  reinterpret_cast<char4*>(dst)[i] = o;
}

// ---- 2) fused GEMM + BatchNorm, 256^2 counted-vmcnt pipeline --------------
// C[i][j] = sum_k A[i][k]*Bt[j][k] (i8 -> i32 exact), then
// out = (C - mean_col) * gamma * rsqrt(var_col + eps) + beta, written f32.
// LDS swizzle: row r's 16B chunk c holds global k-chunk (c ^ (r&7)); staging
// applies the XOR on the global address (DMA dest stays linear); readers
// apply the same XOR. Proven 0 bank conflicts.
__global__ __launch_bounds__(512, 2) void gemm_bn_kernel(
    const char* __restrict__ A,    // [M][K] i8
    const char* __restrict__ Bt,   // [N][K] i8
    float* __restrict__ C,         // [M][N] f32 (final output)
    float* __restrict__ colSum,    // [N] (pre-zeroed)
    float* __restrict__ colSq,     // [N] (pre-zeroed)
    int* __restrict__ barriers,    // [16 * BAR_STRIDE] (pre-zeroed)
    const float* __restrict__ gamma,
    const float* __restrict__ beta,
    int M, int N, int K) {
  __shared__ __align__(16) char sA[2][BM * BKI];  // 2 x 32 KiB
  __shared__ __align__(16) char sB[2][BN * BKI];  // 2 x 32 KiB  (128 KiB tot)

  const int tid  = threadIdx.x;
  const int wave = tid >> 6;
  const int lane = tid & 63;

  // consecutive block-ids share the same B panel (L2 locality)
  const int nby = M / BM;            // row-blocks per column panel (32)
  const int panel = blockIdx.x / nby;
  const int rowBlock = (blockIdx.x % nby) * BM;
  const int colBlock = panel * BN;

  // staging: each wave stages rows [wave*32, wave*32+32) of A and of B.
  // One call = 64 lanes x 16B = 8 rows x 128B; 4 calls per tensor per tile.
  const int laneRow = lane >> 3;                 // 0..7 (== row & 7)
  const int cch     = lane & 7;                  // chunk slot 0..7
  const int swz     = ((cch ^ laneRow) & 7) * 16;  // global k-byte offset

  const char* Ag = A  + (size_t)(rowBlock + wave * 32 + laneRow) * K + swz;
  const char* Bg = Bt + (size_t)(colBlock + wave * 32 + laneRow) * K + swz;

  const int f    = lane & 15;  // m (A) / n (B) index within fragment
  const int quad = lane >> 4;  // k-group selector
  const int f7   = f & 7;
  const int wm = (wave >> 2) * 128;  // wave M-origin (2 waves in M)
  const int wn = (wave & 3) * 64;    // wave N-origin (4 waves in N)

  int32x4 acc[8][4] = {};  // [im 0..7][in 0..3] -> 128 x 16x16 tile

  const int NT = K / BKI;  // 16 K-tiles

  // prologue: stage tile 0 into buffer 0 (8 calls per wave)
#pragma unroll
  for (int j = 0; j < 4; ++j) {
    load16_lds(Ag + (size_t)(j * 8) * K, &sA[0][(wave * 32 + j * 8) * BKI]);
    load16_lds(Bg + (size_t)(j * 8) * K, &sB[0][(wave * 32 + j * 8) * BKI]);
  }

  for (int u = 0; u < NT; ++u) {
    const int cur = u & 1;

    // ---- boundary: prefetch tile u+1 into freed buffer, counted wait ----
    // Freed-buffer safety: tile u-1's phase-3 barrier guaranteed all waves'
    // ds_reads of buf[cur^1] retired (operands consumed by MFMAs) before
    // any wave issues these writes.
    if (u + 1 < NT) {
      const size_t gk = (size_t)(u + 1) * BKI;
      char* dA = &sA[cur ^ 1][0];
      char* dB = &sB[cur ^ 1][0];
#pragma unroll
      for (int j = 0; j < 4; ++j) {
        load16_lds(Ag + gk + (size_t)(j * 8) * K,
                   dA + (wave * 32 + j * 8) * BKI);
        load16_lds(Bg + gk + (size_t)(j * 8) * K,
                   dB + (wave * 32 + j * 8) * BKI);
      }
      // 16 outstanding (8 tile-u oldest + 8 tile-u+1): wait the oldest 8.
      asm volatile("s_waitcnt vmcnt(8)" ::: "memory");
    } else {
      asm volatile("s_waitcnt vmcnt(0)" ::: "memory");
    }
    __builtin_amdgcn_s_barrier();      // all waves' tile-u loads visible
    __builtin_amdgcn_sched_barrier(0); // no hoisting across the barrier

    const char* sAc = sA[cur];
    const char* sBc = sB[cur];

    int32x4 af[4][2];  // A-frags for current M-half, reused across 2 phases
#pragma unroll
    for (int q = 0; q < 4; ++q) {  // phase: (mh,nh) quadrant of wave output
      const int mh = q >> 1, nh = q & 1;
      if (nh == 0) {
#pragma unroll
        for (int mi = 0; mi < 4; ++mi)
#pragma unroll
          for (int s = 0; s < 2; ++s)
            af[mi][s] = *reinterpret_cast<const int32x4*>(
                &sAc[(wm + mh * 64 + mi * 16 + f) * BKI +
                     (((s * 4 + quad) ^ f7) * 16)]);
      }
      int32x4 bf_[2][2];
#pragma unroll
      for (int ni = 0; ni < 2; ++ni)
#pragma unroll
        for (int s = 0; s < 2; ++s)
          bf_[ni][s] = *reinterpret_cast<const int32x4*>(
              &sBc[(wn + nh * 32 + ni * 16 + f) * BKI +
                   (((s * 4 + quad) ^ f7) * 16)]);

      __builtin_amdgcn_s_barrier();  // raw: loads for u+1 stay in flight
      __builtin_amdgcn_s_setprio(1);
#pragma unroll
      for (int mi = 0; mi < 4; ++mi)
#pragma unroll
        for (int ni = 0; ni < 2; ++ni)
#pragma unroll
          for (int s = 0; s < 2; ++s)
            acc[mh * 4 + mi][nh * 2 + ni] =
                __builtin_amdgcn_mfma_i32_16x16x64_i8(
                    af[mi][s], bf_[ni][s], acc[mh * 4 + mi][nh * 2 + ni],
                    0, 0, 0);
      __builtin_amdgcn_s_setprio(0);
      __builtin_amdgcn_s_barrier();
    }
  }

  // ---- column stats: C/D layout col = lane&15, row = quad*4 + reg ---------
#pragma unroll
  for (int in = 0; in < 4; ++in) {
    const int col = colBlock + wn + in * 16 + f;
    float s = 0.f, sq = 0.f;
#pragma unroll
    for (int im = 0; im < 8; ++im)
#pragma unroll
      for (int r = 0; r < 4; ++r) {
        const float fv = (float)acc[im][in][r];
        s += fv;
        sq += fv * fv;
      }
    s  += __shfl_xor(s, 16);  s  += __shfl_xor(s, 32);
    sq += __shfl_xor(sq, 16); sq += __shfl_xor(sq, 32);
    if (quad == 0) {
      atomicAdd(&colSum[col], s);
      atomicAdd(&colSq[col], sq);
    }
  }

  // prefetch gamma/beta for the epilogue (latency hides under the barrier)
  float gmv = 0.f, btv = 0.f;
  if (tid < BN) {
    gmv = gamma[colBlock + tid];
    btv = beta[colBlock + tid];
  }

  // ---- per-panel grid barrier (no HW fences; R11-proven) ------------------
  // Panel p's columns touched only by its own nby row-blocks. All 256
  // blocks co-resident (128KiB LDS -> 1 block/CU x 256 CUs): no deadlock.
  __syncthreads();  // drains vmcnt: this block's stat atomics done at L3
  if (tid == 0) {
    int* bar = barriers + panel * BAR_STRIDE;
    __hip_atomic_fetch_add(bar, 1, __ATOMIC_RELAXED,
                           __HIP_MEMORY_SCOPE_AGENT);
    while (__hip_atomic_load(bar, __ATOMIC_RELAXED,
                             __HIP_MEMORY_SCOPE_AGENT) < nby) {
      __builtin_amdgcn_s_sleep(8);
    }
    asm volatile("" ::: "memory");  // compiler-only ordering; no L2 inv
  }
  __syncthreads();

  // ---- stage per-column (scale, shift) in LDS (aliased on sA) -------------
  float2* sSC = reinterpret_cast<float2*>(&sA[0][0]);  // 256 pairs = 2 KiB
  if (tid < BN) {
    const int col = colBlock + tid;
    const float s  = __hip_atomic_load(&colSum[col], __ATOMIC_RELAXED,
                                       __HIP_MEMORY_SCOPE_AGENT);
    const float sq = __hip_atomic_load(&colSq[col], __ATOMIC_RELAXED,
                                       __HIP_MEMORY_SCOPE_AGENT);
    const float invM = 1.0f / (float)M;
    const float mu  = s * invM;
    const float var = sq * invM - mu * mu;
    const float sc  = gmv * rsqrtf(var + EPS_BN);
    const float sh  = btv - mu * sc;
    sSC[tid] = make_float2(sc, sh);
  }
  __syncthreads();

  // ---- normalize in registers, write final f32 ----------------------------
#pragma unroll
  for (int in = 0; in < 4; ++in) {
    const int lc  = wn + in * 16 + f;  // block-local column
    const float2 ss = sSC[lc];
    const int col = colBlock + lc;
#pragma unroll
    for (int im = 0; im < 8; ++im) {
      float* Cp = C + (size_t)(rowBlock + wm + im * 16 + quad * 4) * N + col;
#pragma unroll
      for (int r = 0; r < 4; ++r)
        Cp[(size_t)r * N] = (float)acc[im][in][r] * ss.x + ss.y;
    }
  }
}

// ---------------------------------------------------------------------------
extern "C" void kernel_launch(void* const* d_in, const int* in_sizes, int n_in,
                              void* d_out, int out_size, void* d_ws,
                              size_t ws_size, hipStream_t stream) {
  const float* x     = (const float*)d_in[0];
  const float* w     = (const float*)d_in[1];
  const float* gamma = (const float*)d_in[2];
  const float* beta  = (const float*)d_in[3];
  float* C = (float*)d_out;

  const int N = in_sizes[2];      // OUT
  const int K = in_sizes[1] / N;  // IN
  const int M = in_sizes[0] / K;  // batch

  // workspace: [A i8 M*K][B i8 N*K][colSum N][colSq N][barriers 16*32 ints]
  char* ws = (char*)d_ws;
  char* Abin = ws;
  char* Bbin = ws + (size_t)M * K;
  float* stats = (float*)(ws + (size_t)M * K + (size_t)N * K);
  float* colSum = stats;
  float* colSq  = stats + N;
  int* barriers = (int*)(stats + 2 * N);

  {
    int nx4 = (M * K) / 4;
    int ntot4 = (M * K + N * K) / 4;
    // zero colSum, colSq, and the 16 padded barrier counters
    binarize_kernel<<<(ntot4 + 255) / 256, 256, 0, stream>>>(
        x, w, Abin, Bbin, stats, nx4, ntot4, 2 * N + 16 * BAR_STRIDE);
  }

  {
    const int nTiles = (M / BM) * (N / BN);  // 256 = 256 CUs x 1 block
    gemm_bn_kernel<<<nTiles, 512, 0, stream>>>(Abin, Bbin, C, colSum, colSq,
                                               barriers, gamma, beta, M, N, K);
  }
}

// Round 8
// 166.082 us; speedup vs baseline: 1.0399x; 1.0399x over previous
//
#include <hip/hip_runtime.h>
#include <stdint.h>

// ---------------------------------------------------------------------------
// BNNLinear: out = BatchNorm( sign(x) @ sign(W)^T )
//   x: [M, K] f32, W: [N, K] f32, gamma/beta: [N] f32  ->  out: [M, N] f32
//
// Round 14 (revert R13; on round 12's 256^2 4-phase kernel, 50.0us):
//   R13 post-mortem: counted-vmcnt + boundary-burst staging REGRESSED
//   (50->58.5). The waited-on loads were issued a full tile earlier, so the
//   wait wasn't the cost -- the burst + "memory"-clobbered asm +
//   sched_barrier(0) pinning (m141 failure mode) were. Revert wholesale.
//   R14 = R12 with ONE change: staging issued EARLY in the tile --
//   4 A-loads in phase 0, 4 B-loads in phase 1 (R12 spread 2/phase through
//   phase 3, so the boundary __syncthreads drained loads issued only ~600cyc
//   before). Now the drain waits on loads >= 2-3 phases (~1200-1900 cyc
//   >> 900cyc HBM) old -> near-no-op, with no inline asm, no pinning.
//   Buffer safety: buf[nxt] readers (tile u-1's phases) all retired at the
//   boundary barrier preceding phase 0.
//   Stats + per-panel no-fence spin barrier + in-reg BN epilogue unchanged
//   (R11-proven). XOR swizzle unchanged (0 bank conflicts).
// ---------------------------------------------------------------------------

typedef int int32x4 __attribute__((ext_vector_type(4)));

#define BM 256
#define BN 256
#define BKI 128  // i8 k-bytes per LDS tile
#define EPS_BN 1e-5f
#define BAR_STRIDE 32  // ints between panel counters (128B, no false sharing)

__device__ __forceinline__ void load16_lds(const void* g, void* l) {
  // 16B per lane, LDS dest = wave-uniform base + lane*16 (linear, no scatter)
  __builtin_amdgcn_global_load_lds(
      (const __attribute__((address_space(1))) void*)g,
      (__attribute__((address_space(3))) void*)l,
      16, 0, 0);
}

__device__ __forceinline__ char sgn(float v) {
  return v > 0.f ? (char)1 : (v < 0.f ? (char)-1 : (char)0);
}

// ---- 1) binarize f32 -> i8 sign (both tensors) + zero stats+barriers ------
__global__ void binarize_kernel(const float* __restrict__ x,
                                const float* __restrict__ w,
                                char* __restrict__ Ab, char* __restrict__ Bb,
                                float* __restrict__ stats,  // colSum|colSq|bar
                                int nx4, int ntot4, int n2) {
  int idx = blockIdx.x * blockDim.x + threadIdx.x;
  if (idx < n2) stats[idx] = 0.f;  // 0.0f bit pattern == int 0
  if (idx >= ntot4) return;
  const float4* src;
  char* dst;
  int i;
  if (idx < nx4) {
    src = reinterpret_cast<const float4*>(x); dst = Ab; i = idx;
  } else {
    src = reinterpret_cast<const float4*>(w); dst = Bb; i = idx - nx4;
  }
  float4 v = src[i];
  char4 o;
  o.x = sgn(v.x); o.y = sgn(v.y); o.z = sgn(v.z); o.w = sgn(v.w);
  reinterpret_cast<char4*>(dst)[i] = o;
}

// ---- 2) fused GEMM + BatchNorm, 256^2 4-phase schedule --------------------
// C[i][j] = sum_k A[i][k]*Bt[j][k] (i8 -> i32 exact), then
// out = (C - mean_col) * gamma * rsqrt(var_col + eps) + beta, written f32.
// LDS swizzle: row r's 16B chunk c holds global k-chunk (c ^ (r&7)); staging
// applies the XOR on the global address (DMA dest stays linear); readers
// apply the same XOR. Proven 0 bank conflicts.
__global__ __launch_bounds__(512, 2) void gemm_bn_kernel(
    const char* __restrict__ A,    // [M][K] i8
    const char* __restrict__ Bt,   // [N][K] i8
    float* __restrict__ C,         // [M][N] f32 (final output)
    float* __restrict__ colSum,    // [N] (pre-zeroed)
    float* __restrict__ colSq,     // [N] (pre-zeroed)
    int* __restrict__ barriers,    // [16 * BAR_STRIDE] (pre-zeroed)
    const float* __restrict__ gamma,
    const float* __restrict__ beta,
    int M, int N, int K) {
  __shared__ __align__(16) char sA[2][BM * BKI];  // 2 x 32 KiB
  __shared__ __align__(16) char sB[2][BN * BKI];  // 2 x 32 KiB  (128 KiB tot)

  const int tid  = threadIdx.x;
  const int wave = tid >> 6;
  const int lane = tid & 63;

  // consecutive block-ids share the same B panel (L2 locality)
  const int nby = M / BM;            // row-blocks per column panel (32)
  const int panel = blockIdx.x / nby;
  const int rowBlock = (blockIdx.x % nby) * BM;
  const int colBlock = panel * BN;

  // staging: each wave stages rows [wave*32, wave*32+32) of A and of B.
  // One call = 64 lanes x 16B = 8 rows x 128B; 4 calls per tensor per tile.
  const int laneRow = lane >> 3;                 // 0..7 (== row & 7)
  const int cch     = lane & 7;                  // chunk slot 0..7
  const int swz     = ((cch ^ laneRow) & 7) * 16;  // global k-byte offset

  const char* Ag = A  + (size_t)(rowBlock + wave * 32 + laneRow) * K + swz;
  const char* Bg = Bt + (size_t)(colBlock + wave * 32 + laneRow) * K + swz;

  const int f    = lane & 15;  // m (A) / n (B) index within fragment
  const int quad = lane >> 4;  // k-group selector
  const int f7   = f & 7;
  const int wm = (wave >> 2) * 128;  // wave M-origin (2 waves in M)
  const int wn = (wave & 3) * 64;    // wave N-origin (4 waves in N)

  int32x4 acc[8][4] = {};  // [im 0..7][in 0..3] -> 128 x 16x16 tile

  const int NT = K / BKI;  // 16 K-tiles

  // prologue: stage tile 0 into buffer 0 (8 calls per wave)
#pragma unroll
  for (int j = 0; j < 4; ++j) {
    load16_lds(Ag + (size_t)(j * 8) * K, &sA[0][(wave * 32 + j * 8) * BKI]);
    load16_lds(Bg + (size_t)(j * 8) * K, &sB[0][(wave * 32 + j * 8) * BKI]);
  }

  for (int t = 0; t < NT; ++t) {
    const int cur = t & 1;
    const int nxt = cur ^ 1;
    const char* sAc = sA[cur];
    const char* sBc = sB[cur];
    const size_t gkn = (size_t)(t + 1) * BKI;
    const bool pre = (t + 1 < NT);

    // tile boundary: compiler emits s_waitcnt vmcnt(0)+lgkmcnt(0)+s_barrier.
    // With early staging (phases 0-1), the youngest outstanding load was
    // issued >= 2-3 phases (~1200-1900 cyc) ago -> the drain is a near-no-op.
    __syncthreads();

    int32x4 af[4][2];  // A-frags for current M-half, reused across 2 phases
#pragma unroll
    for (int q = 0; q < 4; ++q) {  // phase: (mh,nh) quadrant of wave output
      const int mh = q >> 1, nh = q & 1;
      if (nh == 0) {
#pragma unroll
        for (int mi = 0; mi < 4; ++mi)
#pragma unroll
          for (int s = 0; s < 2; ++s)
            af[mi][s] = *reinterpret_cast<const int32x4*>(
                &sAc[(wm + mh * 64 + mi * 16 + f) * BKI +
                     (((s * 4 + quad) ^ f7) * 16)]);
      }
      int32x4 bf_[2][2];
#pragma unroll
      for (int ni = 0; ni < 2; ++ni)
#pragma unroll
        for (int s = 0; s < 2; ++s)
          bf_[ni][s] = *reinterpret_cast<const int32x4*>(
              &sBc[(wn + nh * 32 + ni * 16 + f) * BKI +
                   (((s * 4 + quad) ^ f7) * 16)]);

      // staging for tile t+1, issued EARLY: all A in phase 0, all B in
      // phase 1 (phases 2-3 issue nothing). Loads stay in flight across
      // the intra-tile barriers; drained by the next boundary syncthreads.
      if (pre) {
        if (q == 0) {
#pragma unroll
          for (int j = 0; j < 4; ++j)
            load16_lds(Ag + gkn + (size_t)(j * 8) * K,
                       &sA[nxt][(wave * 32 + j * 8) * BKI]);
        } else if (q == 1) {
#pragma unroll
          for (int j = 0; j < 4; ++j)
            load16_lds(Bg + gkn + (size_t)(j * 8) * K,
                       &sB[nxt][(wave * 32 + j * 8) * BKI]);
        }
      }

      __builtin_amdgcn_s_barrier();  // raw: next-tile loads stay in flight
      __builtin_amdgcn_s_setprio(1);
#pragma unroll
      for (int mi = 0; mi < 4; ++mi)
#pragma unroll
        for (int ni = 0; ni < 2; ++ni)
#pragma unroll
          for (int s = 0; s < 2; ++s)
            acc[mh * 4 + mi][nh * 2 + ni] =
                __builtin_amdgcn_mfma_i32_16x16x64_i8(
                    af[mi][s], bf_[ni][s], acc[mh * 4 + mi][nh * 2 + ni],
                    0, 0, 0);
      __builtin_amdgcn_s_setprio(0);
      __builtin_amdgcn_s_barrier();
    }
  }

  // ---- column stats: C/D layout col = lane&15, row = quad*4 + reg ---------
#pragma unroll
  for (int in = 0; in < 4; ++in) {
    const int col = colBlock + wn + in * 16 + f;
    float s = 0.f, sq = 0.f;
#pragma unroll
    for (int im = 0; im < 8; ++im)
#pragma unroll
      for (int r = 0; r < 4; ++r) {
        const float fv = (float)acc[im][in][r];
        s += fv;
        sq += fv * fv;
      }
    s  += __shfl_xor(s, 16);  s  += __shfl_xor(s, 32);
    sq += __shfl_xor(sq, 16); sq += __shfl_xor(sq, 32);
    if (quad == 0) {
      atomicAdd(&colSum[col], s);
      atomicAdd(&colSq[col], sq);
    }
  }

  // prefetch gamma/beta for the epilogue (latency hides under the barrier)
  float gmv = 0.f, btv = 0.f;
  if (tid < BN) {
    gmv = gamma[colBlock + tid];
    btv = beta[colBlock + tid];
  }

  // ---- per-panel grid barrier (no HW fences; R11-proven) ------------------
  // Panel p's columns touched only by its own nby row-blocks. All 256
  // blocks co-resident (128KiB LDS -> 1 block/CU x 256 CUs): no deadlock.
  __syncthreads();  // drains vmcnt: this block's stat atomics done at L3
  if (tid == 0) {
    int* bar = barriers + panel * BAR_STRIDE;
    __hip_atomic_fetch_add(bar, 1, __ATOMIC_RELAXED,
                           __HIP_MEMORY_SCOPE_AGENT);
    while (__hip_atomic_load(bar, __ATOMIC_RELAXED,
                             __HIP_MEMORY_SCOPE_AGENT) < nby) {
      __builtin_amdgcn_s_sleep(8);
    }
    asm volatile("" ::: "memory");  // compiler-only ordering; no L2 inv
  }
  __syncthreads();

  // ---- stage per-column (scale, shift) in LDS (aliased on sA) -------------
  float2* sSC = reinterpret_cast<float2*>(&sA[0][0]);  // 256 pairs = 2 KiB
  if (tid < BN) {
    const int col = colBlock + tid;
    const float s  = __hip_atomic_load(&colSum[col], __ATOMIC_RELAXED,
                                       __HIP_MEMORY_SCOPE_AGENT);
    const float sq = __hip_atomic_load(&colSq[col], __ATOMIC_RELAXED,
                                       __HIP_MEMORY_SCOPE_AGENT);
    const float invM = 1.0f / (float)M;
    const float mu  = s * invM;
    const float var = sq * invM - mu * mu;
    const float sc  = gmv * rsqrtf(var + EPS_BN);
    const float sh  = btv - mu * sc;
    sSC[tid] = make_float2(sc, sh);
  }
  __syncthreads();

  // ---- normalize in registers, write final f32 ----------------------------
#pragma unroll
  for (int in = 0; in < 4; ++in) {
    const int lc  = wn + in * 16 + f;  // block-local column
    const float2 ss = sSC[lc];
    const int col = colBlock + lc;
#pragma unroll
    for (int im = 0; im < 8; ++im) {
      float* Cp = C + (size_t)(rowBlock + wm + im * 16 + quad * 4) * N + col;
#pragma unroll
      for (int r = 0; r < 4; ++r)
        Cp[(size_t)r * N] = (float)acc[im][in][r] * ss.x + ss.y;
    }
  }
}

// ---------------------------------------------------------------------------
extern "C" void kernel_launch(void* const* d_in, const int* in_sizes, int n_in,
                              void* d_out, int out_size, void* d_ws,
                              size_t ws_size, hipStream_t stream) {
  const float* x     = (const float*)d_in[0];
  const float* w     = (const float*)d_in[1];
  const float* gamma = (const float*)d_in[2];
  const float* beta  = (const float*)d_in[3];
  float* C = (float*)d_out;

  const int N = in_sizes[2];      // OUT
  const int K = in_sizes[1] / N;  // IN
  const int M = in_sizes[0] / K;  // batch

  // workspace: [A i8 M*K][B i8 N*K][colSum N][colSq N][barriers 16*32 ints]
  char* ws = (char*)d_ws;
  char* Abin = ws;
  char* Bbin = ws + (size_t)M * K;
  float* stats = (float*)(ws + (size_t)M * K + (size_t)N * K);
  float* colSum = stats;
  float* colSq  = stats + N;
  int* barriers = (int*)(stats + 2 * N);

  {
    int nx4 = (M * K) / 4;
    int ntot4 = (M * K + N * K) / 4;
    // zero colSum, colSq, and the 16 padded barrier counters
    binarize_kernel<<<(ntot4 + 255) / 256, 256, 0, stream>>>(
        x, w, Abin, Bbin, stats, nx4, ntot4, 2 * N + 16 * BAR_STRIDE);
  }

  {
    const int nTiles = (M / BM) * (N / BN);  // 256 = 256 CUs x 1 block
    gemm_bn_kernel<<<nTiles, 512, 0, stream>>>(Abin, Bbin, C, colSum, colSq,
                                               barriers, gamma, beta, M, N, K);
  }
}

// Round 9
// 164.872 us; speedup vs baseline: 1.0475x; 1.0073x over previous
//
#include <hip/hip_runtime.h>
#include <stdint.h>

// ---------------------------------------------------------------------------
// BNNLinear: out = BatchNorm( sign(x) @ sign(W)^T )
//   x: [M, K] f32, W: [N, K] f32, gamma/beta: [N] f32  ->  out: [M, N] f32
//
// Round 15 (on R12/R14's 256^2 4-phase kernel, best 50.0us):
//   Schedule lever exhausted (R12 spread=50.0, R13 counted=58.5, R14
//   early=52.6). i8 diagnosis: 16x16x64 gives HALF the MFMA instructions
//   per LDS byte vs bf16 (K=64/inst), so the phase template can't hide
//   LDS under MFMA issue. Fix: v_mfma_i32_32x32x32_i8:
//   - same ops in half the instructions; 32x32 i8 ceiling +12% (4404 TOPS);
//   - B frags read ONCE per tile into regs (8 b128) instead of per-M-half
//     (16): LDS traffic 32->24 reads/tile/wave;
//   - C/D layout col=lane&31, row=(reg&3)+8*(reg>>2)+4*(lane>>5) (verified
//     m74/m101); exact-int refcheck catches any layout error.
//   Structure otherwise IDENTICAL to R12: 4 phases (now one per 32-row
//   M-block), 2-2-2-2 staging spread, XOR swizzle (conflict-free for the
//   32-row read: 16-lane service group spans 8 chunk slots x 2 = free),
//   boundary __syncthreads, fused-BN epilogue + no-fence spin barrier.
// ---------------------------------------------------------------------------

typedef int int32x4 __attribute__((ext_vector_type(4)));
typedef int int32x16 __attribute__((ext_vector_type(16)));

#define BM 256
#define BN 256
#define BKI 128  // i8 k-bytes per LDS tile
#define EPS_BN 1e-5f
#define BAR_STRIDE 32  // ints between panel counters (128B, no false sharing)

__device__ __forceinline__ void load16_lds(const void* g, void* l) {
  // 16B per lane, LDS dest = wave-uniform base + lane*16 (linear, no scatter)
  __builtin_amdgcn_global_load_lds(
      (const __attribute__((address_space(1))) void*)g,
      (__attribute__((address_space(3))) void*)l,
      16, 0, 0);
}

__device__ __forceinline__ char sgn(float v) {
  return v > 0.f ? (char)1 : (v < 0.f ? (char)-1 : (char)0);
}

// ---- 1) binarize f32 -> i8 sign (both tensors) + zero stats+barriers ------
__global__ void binarize_kernel(const float* __restrict__ x,
                                const float* __restrict__ w,
                                char* __restrict__ Ab, char* __restrict__ Bb,
                                float* __restrict__ stats,  // colSum|colSq|bar
                                int nx4, int ntot4, int n2) {
  int idx = blockIdx.x * blockDim.x + threadIdx.x;
  if (idx < n2) stats[idx] = 0.f;  // 0.0f bit pattern == int 0
  if (idx >= ntot4) return;
  const float4* src;
  char* dst;
  int i;
  if (idx < nx4) {
    src = reinterpret_cast<const float4*>(x); dst = Ab; i = idx;
  } else {
    src = reinterpret_cast<const float4*>(w); dst = Bb; i = idx - nx4;
  }
  float4 v = src[i];
  char4 o;
  o.x = sgn(v.x); o.y = sgn(v.y); o.z = sgn(v.z); o.w = sgn(v.w);
  reinterpret_cast<char4*>(dst)[i] = o;
}

// ---- 2) fused GEMM + BatchNorm, 256^2 4-phase, 32x32x32 i8 MFMA -----------
// C[i][j] = sum_k A[i][k]*Bt[j][k] (i8 -> i32 exact), then
// out = (C - mean_col) * gamma * rsqrt(var_col + eps) + beta, written f32.
// LDS swizzle: row r's 16B chunk c holds global k-chunk (c ^ (r&7)); staging
// applies the XOR on the global address (DMA dest stays linear); readers
// apply the same XOR. Proven 0 bank conflicts.
__global__ __launch_bounds__(512, 2) void gemm_bn_kernel(
    const char* __restrict__ A,    // [M][K] i8
    const char* __restrict__ Bt,   // [N][K] i8
    float* __restrict__ C,         // [M][N] f32 (final output)
    float* __restrict__ colSum,    // [N] (pre-zeroed)
    float* __restrict__ colSq,     // [N] (pre-zeroed)
    int* __restrict__ barriers,    // [16 * BAR_STRIDE] (pre-zeroed)
    const float* __restrict__ gamma,
    const float* __restrict__ beta,
    int M, int N, int K) {
  __shared__ __align__(16) char sA[2][BM * BKI];  // 2 x 32 KiB
  __shared__ __align__(16) char sB[2][BN * BKI];  // 2 x 32 KiB  (128 KiB tot)

  const int tid  = threadIdx.x;
  const int wave = tid >> 6;
  const int lane = tid & 63;

  // consecutive block-ids share the same B panel (L2 locality)
  const int nby = M / BM;            // row-blocks per column panel (32)
  const int panel = blockIdx.x / nby;
  const int rowBlock = (blockIdx.x % nby) * BM;
  const int colBlock = panel * BN;

  // staging: each wave stages rows [wave*32, wave*32+32) of A and of B.
  // One call = 64 lanes x 16B = 8 rows x 128B; 4 calls per tensor per tile.
  const int laneRow = lane >> 3;                 // 0..7 (== row & 7)
  const int cch     = lane & 7;                  // chunk slot 0..7
  const int swz     = ((cch ^ laneRow) & 7) * 16;  // global k-byte offset

  const char* Ag = A  + (size_t)(rowBlock + wave * 32 + laneRow) * K + swz;
  const char* Bg = Bt + (size_t)(colBlock + wave * 32 + laneRow) * K + swz;

  const int lane31 = lane & 31;  // row (A) / col (B) within 32x32 fragment
  const int hi     = lane >> 5;  // k-half selector (16 k-bytes each)
  const int wm = (wave >> 2) * 128;  // wave M-origin (2 waves in M)
  const int wn = (wave & 3) * 64;    // wave N-origin (4 waves in N)

  int32x16 acc[4][2] = {};  // [mi 32-row block][ni 32-col block]

  const int NT = K / BKI;  // 16 K-tiles

  // prologue: stage tile 0 into buffer 0 (8 calls per wave)
#pragma unroll
  for (int j = 0; j < 4; ++j) {
    load16_lds(Ag + (size_t)(j * 8) * K, &sA[0][(wave * 32 + j * 8) * BKI]);
    load16_lds(Bg + (size_t)(j * 8) * K, &sB[0][(wave * 32 + j * 8) * BKI]);
  }

  for (int t = 0; t < NT; ++t) {
    const int cur = t & 1;
    const int nxt = cur ^ 1;
    const char* sAc = sA[cur];
    const char* sBc = sB[cur];
    const size_t gkn = (size_t)(t + 1) * BKI;
    const bool pre = (t + 1 < NT);

    // tile boundary: compiler-emitted vmcnt/lgkm drain + barrier. The
    // youngest outstanding staging load was issued 2 phases ago.
    __syncthreads();

    // B fragments for the whole tile, read ONCE (8 x ds_read_b128).
    // Operand layout 32x32x32 i8: col = lane31, k = hi*16 + [0..16).
    int32x16 bf_[2];  // wait-free packing: [ni] x 4 k-slices x int32x4
    int32x4* bfv = reinterpret_cast<int32x4*>(&bf_[0]);
#pragma unroll
    for (int ni = 0; ni < 2; ++ni) {
      const int row = wn + ni * 32 + lane31;
#pragma unroll
      for (int ks = 0; ks < 4; ++ks) {
        const int chunk = ((ks * 2 + hi) ^ (row & 7)) * 16;
        bfv[ni * 4 + ks] = *reinterpret_cast<const int32x4*>(
            &sBc[row * BKI + chunk]);
      }
    }

#pragma unroll
    for (int q = 0; q < 4; ++q) {  // phase q = M-block mi
      // A fragments for this 32-row block (4 x ds_read_b128)
      int32x4 af[4];
      const int arow = wm + q * 32 + lane31;
#pragma unroll
      for (int ks = 0; ks < 4; ++ks) {
        const int chunk = ((ks * 2 + hi) ^ (arow & 7)) * 16;
        af[ks] = *reinterpret_cast<const int32x4*>(&sAc[arow * BKI + chunk]);
      }

      // staging for tile t+1: 2 calls/phase (A in q0-1, B in q2-3; the
      // measured-best R12 spread). Loads stay in flight across barriers.
      if (pre) {
        if (q < 2) {
#pragma unroll
          for (int j = 0; j < 2; ++j) {
            const int part = q * 2 + j;
            load16_lds(Ag + gkn + (size_t)(part * 8) * K,
                       &sA[nxt][(wave * 32 + part * 8) * BKI]);
          }
        } else {
#pragma unroll
          for (int j = 0; j < 2; ++j) {
            const int part = (q - 2) * 2 + j;
            load16_lds(Bg + gkn + (size_t)(part * 8) * K,
                       &sB[nxt][(wave * 32 + part * 8) * BKI]);
          }
        }
      }

      __builtin_amdgcn_s_barrier();  // raw: next-tile loads stay in flight
      __builtin_amdgcn_s_setprio(1);
#pragma unroll
      for (int ks = 0; ks < 4; ++ks)
#pragma unroll
        for (int ni = 0; ni < 2; ++ni)
          acc[q][ni] = __builtin_amdgcn_mfma_i32_32x32x32_i8(
              af[ks], bfv[ni * 4 + ks], acc[q][ni], 0, 0, 0);
      __builtin_amdgcn_s_setprio(0);
      __builtin_amdgcn_s_barrier();
    }
  }

  // ---- column stats: C/D 32x32 layout col=lane31, row=(r&3)+8(r>>2)+4hi --
#pragma unroll
  for (int ni = 0; ni < 2; ++ni) {
    const int col = colBlock + wn + ni * 32 + lane31;
    float s = 0.f, sq = 0.f;
#pragma unroll
    for (int mi = 0; mi < 4; ++mi)
#pragma unroll
      for (int r = 0; r < 16; ++r) {
        const float fv = (float)acc[mi][ni][r];
        s += fv;
        sq += fv * fv;
      }
    // lanes l and l^32 hold the same column (different row halves)
    s  += __shfl_xor(s, 32);
    sq += __shfl_xor(sq, 32);
    if (hi == 0) {
      atomicAdd(&colSum[col], s);
      atomicAdd(&colSq[col], sq);
    }
  }

  // prefetch gamma/beta for the epilogue (latency hides under the barrier)
  float gmv = 0.f, btv = 0.f;
  if (tid < BN) {
    gmv = gamma[colBlock + tid];
    btv = beta[colBlock + tid];
  }

  // ---- per-panel grid barrier (no HW fences; R11-proven) ------------------
  // Panel p's columns touched only by its own nby row-blocks. All 256
  // blocks co-resident (128KiB LDS -> 1 block/CU x 256 CUs): no deadlock.
  __syncthreads();  // drains vmcnt: this block's stat atomics done at L3
  if (tid == 0) {
    int* bar = barriers + panel * BAR_STRIDE;
    __hip_atomic_fetch_add(bar, 1, __ATOMIC_RELAXED,
                           __HIP_MEMORY_SCOPE_AGENT);
    while (__hip_atomic_load(bar, __ATOMIC_RELAXED,
                             __HIP_MEMORY_SCOPE_AGENT) < nby) {
      __builtin_amdgcn_s_sleep(8);
    }
    asm volatile("" ::: "memory");  // compiler-only ordering; no L2 inv
  }
  __syncthreads();

  // ---- stage per-column (scale, shift) in LDS (aliased on sA) -------------
  float2* sSC = reinterpret_cast<float2*>(&sA[0][0]);  // 256 pairs = 2 KiB
  if (tid < BN) {
    const int col = colBlock + tid;
    const float s  = __hip_atomic_load(&colSum[col], __ATOMIC_RELAXED,
                                       __HIP_MEMORY_SCOPE_AGENT);
    const float sq = __hip_atomic_load(&colSq[col], __ATOMIC_RELAXED,
                                       __HIP_MEMORY_SCOPE_AGENT);
    const float invM = 1.0f / (float)M;
    const float mu  = s * invM;
    const float var = sq * invM - mu * mu;
    const float sc  = gmv * rsqrtf(var + EPS_BN);
    const float sh  = btv - mu * sc;
    sSC[tid] = make_float2(sc, sh);
  }
  __syncthreads();

  // ---- normalize in registers, write final f32 ----------------------------
#pragma unroll
  for (int ni = 0; ni < 2; ++ni) {
    const int lc  = wn + ni * 32 + lane31;  // block-local column
    const float2 ss = sSC[lc];
    const int col = colBlock + lc;
#pragma unroll
    for (int mi = 0; mi < 4; ++mi) {
#pragma unroll
      for (int r = 0; r < 16; ++r) {
        const int row = rowBlock + wm + mi * 32 + (r & 3) + 8 * (r >> 2) +
                        4 * hi;
        C[(size_t)row * N + col] = (float)acc[mi][ni][r] * ss.x + ss.y;
      }
    }
  }
}

// ---------------------------------------------------------------------------
extern "C" void kernel_launch(void* const* d_in, const int* in_sizes, int n_in,
                              void* d_out, int out_size, void* d_ws,
                              size_t ws_size, hipStream_t stream) {
  const float* x     = (const float*)d_in[0];
  const float* w     = (const float*)d_in[1];
  const float* gamma = (const float*)d_in[2];
  const float* beta  = (const float*)d_in[3];
  float* C = (float*)d_out;

  const int N = in_sizes[2];      // OUT
  const int K = in_sizes[1] / N;  // IN
  const int M = in_sizes[0] / K;  // batch

  // workspace: [A i8 M*K][B i8 N*K][colSum N][colSq N][barriers 16*32 ints]
  char* ws = (char*)d_ws;
  char* Abin = ws;
  char* Bbin = ws + (size_t)M * K;
  float* stats = (float*)(ws + (size_t)M * K + (size_t)N * K);
  float* colSum = stats;
  float* colSq  = stats + N;
  int* barriers = (int*)(stats + 2 * N);

  {
    int nx4 = (M * K) / 4;
    int ntot4 = (M * K + N * K) / 4;
    // zero colSum, colSq, and the 16 padded barrier counters
    binarize_kernel<<<(ntot4 + 255) / 256, 256, 0, stream>>>(
        x, w, Abin, Bbin, stats, nx4, ntot4, 2 * N + 16 * BAR_STRIDE);
  }

  {
    const int nTiles = (M / BM) * (N / BN);  // 256 = 256 CUs x 1 block
    gemm_bn_kernel<<<nTiles, 512, 0, stream>>>(Abin, Bbin, C, colSum, colSq,
                                               barriers, gamma, beta, M, N, K);
  }
}

// Round 10
// 161.849 us; speedup vs baseline: 1.0671x; 1.0187x over previous
//
#include <hip/hip_runtime.h>
#include <stdint.h>

// ---------------------------------------------------------------------------
// BNNLinear: out = BatchNorm( sign(x) @ sign(W)^T )
//   x: [M, K] f32, W: [N, K] f32, gamma/beta: [N] f32  ->  out: [M, N] f32
//
// Round 16 (on R15's 32x32x32 kernel, 52.5us, total 164.9us):
//   R15 post-mortem: 32x32 was net-neutral because two effects canceled:
//   WRITE 82->66.5MB (coalesced C-rows, win) vs SQ_LDS_BANK_CONFLICT
//   0 -> 3,145,728 == EXACTLY 4 cycles per ds_read_b128. Mechanism: slot
//   XOR uses only row&7; rows stride 128B = one bank revolution, so lanes
//   {0,8,16,24} (same row&7, same hi) hit the same 16B slot -> 4-way.
//   The 16x16 pattern avoided this only because quad entered the XOR.
//   Fix: TWO-LEVEL swizzle. slot = kc ^ (row&7) ^ ((row>>3)&3):
//   - staging: global chunk (cch ^ laneRow ^ j) per 8-row part j (j is
//     compile-time; DMA dest stays linear);
//   - readers: chunk = (ks*2+hi) ^ (row&7) ^ ((row>>3)&3).
//   Lanes {0,8,16,24} now span 4 distinct slots; 8-lane sequential groups
//   still span 8. Conflict-free under both service orderings.
//   Everything else identical to R15 (4-phase, 2-2-2-2 staging, B-in-regs
//   once/tile, fused-BN epilogue, no-fence per-panel spin barrier).
// ---------------------------------------------------------------------------

typedef int int32x4 __attribute__((ext_vector_type(4)));
typedef int int32x16 __attribute__((ext_vector_type(16)));

#define BM 256
#define BN 256
#define BKI 128  // i8 k-bytes per LDS tile
#define EPS_BN 1e-5f
#define BAR_STRIDE 32  // ints between panel counters (128B, no false sharing)

__device__ __forceinline__ void load16_lds(const void* g, void* l) {
  // 16B per lane, LDS dest = wave-uniform base + lane*16 (linear, no scatter)
  __builtin_amdgcn_global_load_lds(
      (const __attribute__((address_space(1))) void*)g,
      (__attribute__((address_space(3))) void*)l,
      16, 0, 0);
}

__device__ __forceinline__ char sgn(float v) {
  return v > 0.f ? (char)1 : (v < 0.f ? (char)-1 : (char)0);
}

// ---- 1) binarize f32 -> i8 sign (both tensors) + zero stats+barriers ------
__global__ void binarize_kernel(const float* __restrict__ x,
                                const float* __restrict__ w,
                                char* __restrict__ Ab, char* __restrict__ Bb,
                                float* __restrict__ stats,  // colSum|colSq|bar
                                int nx4, int ntot4, int n2) {
  int idx = blockIdx.x * blockDim.x + threadIdx.x;
  if (idx < n2) stats[idx] = 0.f;  // 0.0f bit pattern == int 0
  if (idx >= ntot4) return;
  const float4* src;
  char* dst;
  int i;
  if (idx < nx4) {
    src = reinterpret_cast<const float4*>(x); dst = Ab; i = idx;
  } else {
    src = reinterpret_cast<const float4*>(w); dst = Bb; i = idx - nx4;
  }
  float4 v = src[i];
  char4 o;
  o.x = sgn(v.x); o.y = sgn(v.y); o.z = sgn(v.z); o.w = sgn(v.w);
  reinterpret_cast<char4*>(dst)[i] = o;
}

// ---- 2) fused GEMM + BatchNorm, 256^2 4-phase, 32x32x32 i8 MFMA -----------
// C[i][j] = sum_k A[i][k]*Bt[j][k] (i8 -> i32 exact), then
// out = (C - mean_col) * gamma * rsqrt(var_col + eps) + beta, written f32.
// Two-level LDS swizzle: LDS row R, slot c holds global k-chunk
//   c ^ (R&7) ^ ((R>>3)&3)
// applied on the global source address at staging (DMA dest linear) and on
// the slot index at read time.
__global__ __launch_bounds__(512, 2) void gemm_bn_kernel(
    const char* __restrict__ A,    // [M][K] i8
    const char* __restrict__ Bt,   // [N][K] i8
    float* __restrict__ C,         // [M][N] f32 (final output)
    float* __restrict__ colSum,    // [N] (pre-zeroed)
    float* __restrict__ colSq,     // [N] (pre-zeroed)
    int* __restrict__ barriers,    // [16 * BAR_STRIDE] (pre-zeroed)
    const float* __restrict__ gamma,
    const float* __restrict__ beta,
    int M, int N, int K) {
  __shared__ __align__(16) char sA[2][BM * BKI];  // 2 x 32 KiB
  __shared__ __align__(16) char sB[2][BN * BKI];  // 2 x 32 KiB  (128 KiB tot)

  const int tid  = threadIdx.x;
  const int wave = tid >> 6;
  const int lane = tid & 63;

  // consecutive block-ids share the same B panel (L2 locality)
  const int nby = M / BM;            // row-blocks per column panel (32)
  const int panel = blockIdx.x / nby;
  const int rowBlock = (blockIdx.x % nby) * BM;
  const int colBlock = panel * BN;

  // staging: each wave stages rows [wave*32, wave*32+32) of A and of B.
  // One call = 64 lanes x 16B = 8 rows x 128B; part j covers rows j*8..j*8+7.
  // Global k-byte offset for part j: ((cch ^ laneRow ^ j)&7)*16.
  const int laneRow = lane >> 3;                 // 0..7 (== LDS row & 7)
  const int cch     = lane & 7;                  // dest slot 0..7
  int swzj[4];
#pragma unroll
  for (int j = 0; j < 4; ++j) swzj[j] = ((cch ^ laneRow ^ j) & 7) * 16;

  const char* Ag = A  + (size_t)(rowBlock + wave * 32 + laneRow) * K;
  const char* Bg = Bt + (size_t)(colBlock + wave * 32 + laneRow) * K;

  const int lane31 = lane & 31;  // row (A) / col (B) within 32x32 fragment
  const int hi     = lane >> 5;  // k-half selector (16 k-bytes each)
  const int r2     = (lane31 >> 3) & 3;  // second-level swizzle bits
  const int wm = (wave >> 2) * 128;  // wave M-origin (2 waves in M)
  const int wn = (wave & 3) * 64;    // wave N-origin (4 waves in N)

  int32x16 acc[4][2] = {};  // [mi 32-row block][ni 32-col block]

  const int NT = K / BKI;  // 16 K-tiles

  // prologue: stage tile 0 into buffer 0 (8 calls per wave)
#pragma unroll
  for (int j = 0; j < 4; ++j) {
    load16_lds(Ag + (size_t)(j * 8) * K + swzj[j],
               &sA[0][(wave * 32 + j * 8) * BKI]);
    load16_lds(Bg + (size_t)(j * 8) * K + swzj[j],
               &sB[0][(wave * 32 + j * 8) * BKI]);
  }

  for (int t = 0; t < NT; ++t) {
    const int cur = t & 1;
    const int nxt = cur ^ 1;
    const char* sAc = sA[cur];
    const char* sBc = sB[cur];
    const size_t gkn = (size_t)(t + 1) * BKI;
    const bool pre = (t + 1 < NT);

    // tile boundary: compiler-emitted vmcnt/lgkm drain + barrier. The
    // youngest outstanding staging load was issued 2 phases ago.
    __syncthreads();

    // B fragments for the whole tile, read ONCE (8 x ds_read_b128).
    // Operand layout 32x32x32 i8: col = lane31, k = hi*16 + [0..16).
    int32x16 bf_[2];
    int32x4* bfv = reinterpret_cast<int32x4*>(&bf_[0]);
#pragma unroll
    for (int ni = 0; ni < 2; ++ni) {
      const int row = wn + ni * 32 + lane31;
#pragma unroll
      for (int ks = 0; ks < 4; ++ks) {
        const int chunk = (((ks * 2 + hi) ^ (row & 7) ^ r2) & 7) * 16;
        bfv[ni * 4 + ks] = *reinterpret_cast<const int32x4*>(
            &sBc[row * BKI + chunk]);
      }
    }

#pragma unroll
    for (int q = 0; q < 4; ++q) {  // phase q = M-block mi
      // A fragments for this 32-row block (4 x ds_read_b128)
      int32x4 af[4];
      const int arow = wm + q * 32 + lane31;
#pragma unroll
      for (int ks = 0; ks < 4; ++ks) {
        const int chunk = (((ks * 2 + hi) ^ (arow & 7) ^ r2) & 7) * 16;
        af[ks] = *reinterpret_cast<const int32x4*>(&sAc[arow * BKI + chunk]);
      }

      // staging for tile t+1: 2 calls/phase (A in q0-1, B in q2-3; the
      // measured-best R12 spread). Loads stay in flight across barriers.
      if (pre) {
        if (q < 2) {
#pragma unroll
          for (int j = 0; j < 2; ++j) {
            const int part = q * 2 + j;
            load16_lds(Ag + gkn + (size_t)(part * 8) * K + swzj[part],
                       &sA[nxt][(wave * 32 + part * 8) * BKI]);
          }
        } else {
#pragma unroll
          for (int j = 0; j < 2; ++j) {
            const int part = (q - 2) * 2 + j;
            load16_lds(Bg + gkn + (size_t)(part * 8) * K + swzj[part],
                       &sB[nxt][(wave * 32 + part * 8) * BKI]);
          }
        }
      }

      __builtin_amdgcn_s_barrier();  // raw: next-tile loads stay in flight
      __builtin_amdgcn_s_setprio(1);
#pragma unroll
      for (int ks = 0; ks < 4; ++ks)
#pragma unroll
        for (int ni = 0; ni < 2; ++ni)
          acc[q][ni] = __builtin_amdgcn_mfma_i32_32x32x32_i8(
              af[ks], bfv[ni * 4 + ks], acc[q][ni], 0, 0, 0);
      __builtin_amdgcn_s_setprio(0);
      __builtin_amdgcn_s_barrier();
    }
  }

  // ---- column stats: C/D 32x32 layout col=lane31, row=(r&3)+8(r>>2)+4hi --
#pragma unroll
  for (int ni = 0; ni < 2; ++ni) {
    const int col = colBlock + wn + ni * 32 + lane31;
    float s = 0.f, sq = 0.f;
#pragma unroll
    for (int mi = 0; mi < 4; ++mi)
#pragma unroll
      for (int r = 0; r < 16; ++r) {
        const float fv = (float)acc[mi][ni][r];
        s += fv;
        sq += fv * fv;
      }
    // lanes l and l^32 hold the same column (different row halves)
    s  += __shfl_xor(s, 32);
    sq += __shfl_xor(sq, 32);
    if (hi == 0) {
      atomicAdd(&colSum[col], s);
      atomicAdd(&colSq[col], sq);
    }
  }

  // prefetch gamma/beta for the epilogue (latency hides under the barrier)
  float gmv = 0.f, btv = 0.f;
  if (tid < BN) {
    gmv = gamma[colBlock + tid];
    btv = beta[colBlock + tid];
  }

  // ---- per-panel grid barrier (no HW fences; R11-proven) ------------------
  // Panel p's columns touched only by its own nby row-blocks. All 256
  // blocks co-resident (128KiB LDS -> 1 block/CU x 256 CUs): no deadlock.
  __syncthreads();  // drains vmcnt: this block's stat atomics done at L3
  if (tid == 0) {
    int* bar = barriers + panel * BAR_STRIDE;
    __hip_atomic_fetch_add(bar, 1, __ATOMIC_RELAXED,
                           __HIP_MEMORY_SCOPE_AGENT);
    while (__hip_atomic_load(bar, __ATOMIC_RELAXED,
                             __HIP_MEMORY_SCOPE_AGENT) < nby) {
      __builtin_amdgcn_s_sleep(8);
    }
    asm volatile("" ::: "memory");  // compiler-only ordering; no L2 inv
  }
  __syncthreads();

  // ---- stage per-column (scale, shift) in LDS (aliased on sA) -------------
  float2* sSC = reinterpret_cast<float2*>(&sA[0][0]);  // 256 pairs = 2 KiB
  if (tid < BN) {
    const int col = colBlock + tid;
    const float s  = __hip_atomic_load(&colSum[col], __ATOMIC_RELAXED,
                                       __HIP_MEMORY_SCOPE_AGENT);
    const float sq = __hip_atomic_load(&colSq[col], __ATOMIC_RELAXED,
                                       __HIP_MEMORY_SCOPE_AGENT);
    const float invM = 1.0f / (float)M;
    const float mu  = s * invM;
    const float var = sq * invM - mu * mu;
    const float sc  = gmv * rsqrtf(var + EPS_BN);
    const float sh  = btv - mu * sc;
    sSC[tid] = make_float2(sc, sh);
  }
  __syncthreads();

  // ---- normalize in registers, write final f32 ----------------------------
#pragma unroll
  for (int ni = 0; ni < 2; ++ni) {
    const int lc  = wn + ni * 32 + lane31;  // block-local column
    const float2 ss = sSC[lc];
    const int col = colBlock + lc;
#pragma unroll
    for (int mi = 0; mi < 4; ++mi) {
#pragma unroll
      for (int r = 0; r < 16; ++r) {
        const int row = rowBlock + wm + mi * 32 + (r & 3) + 8 * (r >> 2) +
                        4 * hi;
        C[(size_t)row * N + col] = (float)acc[mi][ni][r] * ss.x + ss.y;
      }
    }
  }
}

// ---------------------------------------------------------------------------
extern "C" void kernel_launch(void* const* d_in, const int* in_sizes, int n_in,
                              void* d_out, int out_size, void* d_ws,
                              size_t ws_size, hipStream_t stream) {
  const float* x     = (const float*)d_in[0];
  const float* w     = (const float*)d_in[1];
  const float* gamma = (const float*)d_in[2];
  const float* beta  = (const float*)d_in[3];
  float* C = (float*)d_out;

  const int N = in_sizes[2];      // OUT
  const int K = in_sizes[1] / N;  // IN
  const int M = in_sizes[0] / K;  // batch

  // workspace: [A i8 M*K][B i8 N*K][colSum N][colSq N][barriers 16*32 ints]
  char* ws = (char*)d_ws;
  char* Abin = ws;
  char* Bbin = ws + (size_t)M * K;
  float* stats = (float*)(ws + (size_t)M * K + (size_t)N * K);
  float* colSum = stats;
  float* colSq  = stats + N;
  int* barriers = (int*)(stats + 2 * N);

  {
    int nx4 = (M * K) / 4;
    int ntot4 = (M * K + N * K) / 4;
    // zero colSum, colSq, and the 16 padded barrier counters
    binarize_kernel<<<(ntot4 + 255) / 256, 256, 0, stream>>>(
        x, w, Abin, Bbin, stats, nx4, ntot4, 2 * N + 16 * BAR_STRIDE);
  }

  {
    const int nTiles = (M / BM) * (N / BN);  // 256 = 256 CUs x 1 block
    gemm_bn_kernel<<<nTiles, 512, 0, stream>>>(Abin, Bbin, C, colSum, colSq,
                                               barriers, gamma, beta, M, N, K);
  }
}

// Round 11
// 149.763 us; speedup vs baseline: 1.1532x; 1.0807x over previous
//
#include <hip/hip_runtime.h>
#include <stdint.h>

// ---------------------------------------------------------------------------
// BNNLinear: out = BatchNorm( sign(x) @ sign(W)^T )
//   x: [M, K] f32, W: [N, K] f32, gamma/beta: [N] f32  ->  out: [M, N] f32
//
// Round 17 (on R16's 32x32x32 i8 kernel, 47.4us, total 161.8us):
//   R16 post-mortem: conflicts 3.1M->0, gemm 52.5->47.4 (predicted). i8
//   compute floor corrected: 137.4 GOP / 4404 TOPS = 31.2us -> only ~5us of
//   schedule left. Remaining lever is the RATE: MX-FP4 (mfma_scale
//   32x32x64 f8f6f4, fmt=4) = 9099 TOPS = 2.07x i8 -> floor 15.1us.
//   sign values {-1,0,+1} are exact in FP4 E2M1 (0x0/0x2/0xA); uniform
//   E8M0 scale 1.0 (0x7F bytes) is layout-independent; any k-permutation
//   mismatch applies to BOTH operands (same binarize packing) -> dot
//   product invariant; C/D layout is shape-determined = R16's verified
//   32x32 mapping; exact-int refcheck catches any error loudly.
//   Bytes halve: staging fetch 24.8->13MB, LDS reads/k halve, binarize
//   writes 20->10MB. Everything else BYTE-IDENTICAL to R16: 4-phase,
//   2-2-2-2 staging spread, two-level swizzle (chunk formula carries over
//   unchanged), no-fence per-panel grid barrier, fused-BN epilogue.
// ---------------------------------------------------------------------------

typedef int int32x4 __attribute__((ext_vector_type(4)));
typedef int int32x8 __attribute__((ext_vector_type(8)));
typedef float f32x16 __attribute__((ext_vector_type(16)));

#define BM 256
#define BN 256
#define BKI 128  // fp4 k-BYTES per LDS tile (= 256 k-elements)
#define EPS_BN 1e-5f
#define BAR_STRIDE 32  // ints between panel counters (128B, no false sharing)
#define SCALE_ONE 0x7F7F7F7F  // E8M0 exponent 127 -> 2^0 = 1.0 per block

__device__ __forceinline__ void load16_lds(const void* g, void* l) {
  // 16B per lane, LDS dest = wave-uniform base + lane*16 (linear, no scatter)
  __builtin_amdgcn_global_load_lds(
      (const __attribute__((address_space(1))) void*)g,
      (__attribute__((address_space(3))) void*)l,
      16, 0, 0);
}

__device__ __forceinline__ int32x8 mk8(int32x4 v) {
  int32x8 r = {v[0], v[1], v[2], v[3], 0, 0, 0, 0};  // fp4 uses low 4 regs
  return r;
}

// fp4 E2M1 encode of sign: +1 -> 0x2, -1 -> 0xA, 0 -> 0x0
__device__ __forceinline__ unsigned enc4(float v) {
  return v > 0.f ? 2u : (v < 0.f ? 10u : 0u);
}

// ---- 1) binarize f32 -> fp4 sign (packed 2/byte) + zero stats+barriers ----
__global__ void binarize_kernel(const float* __restrict__ x,
                                const float* __restrict__ w,
                                unsigned* __restrict__ Ab,
                                unsigned* __restrict__ Bb,
                                float* __restrict__ stats,  // colSum|colSq|bar
                                int nx8, int ntot8, int n2) {
  int idx = blockIdx.x * blockDim.x + threadIdx.x;
  if (idx < n2) stats[idx] = 0.f;  // 0.0f bit pattern == int 0
  if (idx >= ntot8) return;
  const float4* src;
  unsigned* dst;
  int i;
  if (idx < nx8) {
    src = reinterpret_cast<const float4*>(x); dst = Ab; i = idx;
  } else {
    src = reinterpret_cast<const float4*>(w); dst = Bb; i = idx - nx8;
  }
  const float4 s0 = src[2 * i];
  const float4 s1 = src[2 * i + 1];
  // element e -> nibble e (byte b = elems 2b low, 2b+1 high); same packing
  // for A and B -> any HW k-order mismatch cancels in the dot product.
  unsigned out = enc4(s0.x)        | (enc4(s0.y) << 4)  |
                 (enc4(s0.z) << 8) | (enc4(s0.w) << 12) |
                 (enc4(s1.x) << 16)| (enc4(s1.y) << 20) |
                 (enc4(s1.z) << 24)| (enc4(s1.w) << 28);
  dst[i] = out;
}

// ---- 2) fused GEMM + BatchNorm, 256^2 4-phase, MX-FP4 32x32x64 MFMA -------
// C[i][j] = sum_k sign(x)[i][k]*sign(W)[j][k] (fp4 -> f32 exact), then
// out = (C - mean_col) * gamma * rsqrt(var_col + eps) + beta, written f32.
// Two-level LDS swizzle (R16-proven, 0 conflicts): LDS row R, 16B slot c
// holds global k-chunk c ^ (R&7) ^ ((R>>3)&3); applied on the global source
// address at staging (DMA dest linear) and on the slot index at read time.
__global__ __launch_bounds__(512, 2) void gemm_bn_kernel(
    const char* __restrict__ A,    // [M][K/2] fp4-packed
    const char* __restrict__ Bt,   // [N][K/2] fp4-packed
    float* __restrict__ C,         // [M][N] f32 (final output)
    float* __restrict__ colSum,    // [N] (pre-zeroed)
    float* __restrict__ colSq,     // [N] (pre-zeroed)
    int* __restrict__ barriers,    // [16 * BAR_STRIDE] (pre-zeroed)
    const float* __restrict__ gamma,
    const float* __restrict__ beta,
    int M, int N, int K) {
  __shared__ __align__(16) char sA[2][BM * BKI];  // 2 x 32 KiB
  __shared__ __align__(16) char sB[2][BN * BKI];  // 2 x 32 KiB  (128 KiB tot)

  const int tid  = threadIdx.x;
  const int wave = tid >> 6;
  const int lane = tid & 63;
  const int Kb   = K >> 1;  // bytes per row

  // consecutive block-ids share the same B panel (L2 locality)
  const int nby = M / BM;            // row-blocks per column panel (32)
  const int panel = blockIdx.x / nby;
  const int rowBlock = (blockIdx.x % nby) * BM;
  const int colBlock = panel * BN;

  // staging: each wave stages rows [wave*32, wave*32+32) of A and of B.
  // One call = 64 lanes x 16B = 8 rows x 128B; part j covers rows j*8..j*8+7.
  const int laneRow = lane >> 3;                 // 0..7 (== LDS row & 7)
  const int cch     = lane & 7;                  // dest slot 0..7
  int swzj[4];
#pragma unroll
  for (int j = 0; j < 4; ++j) swzj[j] = ((cch ^ laneRow ^ j) & 7) * 16;

  const char* Ag = A  + (size_t)(rowBlock + wave * 32 + laneRow) * Kb;
  const char* Bg = Bt + (size_t)(colBlock + wave * 32 + laneRow) * Kb;

  const int lane31 = lane & 31;  // row (A) / col (B) within 32x32 fragment
  const int hi     = lane >> 5;  // k-half selector (16 k-bytes each)
  const int r2     = (lane31 >> 3) & 3;  // second-level swizzle bits
  const int wm = (wave >> 2) * 128;  // wave M-origin (2 waves in M)
  const int wn = (wave & 3) * 64;    // wave N-origin (4 waves in N)

  f32x16 acc[4][2] = {};  // [mi 32-row block][ni 32-col block]

  const int NT = Kb / BKI;  // 16 K-tiles (256 k-elements each)

  // prologue: stage tile 0 into buffer 0 (8 calls per wave)
#pragma unroll
  for (int j = 0; j < 4; ++j) {
    load16_lds(Ag + (size_t)(j * 8) * Kb + swzj[j],
               &sA[0][(wave * 32 + j * 8) * BKI]);
    load16_lds(Bg + (size_t)(j * 8) * Kb + swzj[j],
               &sB[0][(wave * 32 + j * 8) * BKI]);
  }

  for (int t = 0; t < NT; ++t) {
    const int cur = t & 1;
    const int nxt = cur ^ 1;
    const char* sAc = sA[cur];
    const char* sBc = sB[cur];
    const size_t gkn = (size_t)(t + 1) * BKI;
    const bool pre = (t + 1 < NT);

    // tile boundary: compiler-emitted vmcnt/lgkm drain + barrier. The
    // youngest outstanding staging load was issued 2 phases ago.
    __syncthreads();

    // B fragments for the whole tile, read ONCE (8 x ds_read_b128).
    // Per MFMA k-step ks: lane's 16B = chunk (ks*2 + hi), swizzled.
    int32x4 bfv[8];
#pragma unroll
    for (int ni = 0; ni < 2; ++ni) {
      const int row = wn + ni * 32 + lane31;
#pragma unroll
      for (int ks = 0; ks < 4; ++ks) {
        const int chunk = (((ks * 2 + hi) ^ (row & 7) ^ r2) & 7) * 16;
        bfv[ni * 4 + ks] = *reinterpret_cast<const int32x4*>(
            &sBc[row * BKI + chunk]);
      }
    }

#pragma unroll
    for (int q = 0; q < 4; ++q) {  // phase q = M-block mi
      // A fragments for this 32-row block (4 x ds_read_b128)
      int32x4 af[4];
      const int arow = wm + q * 32 + lane31;
#pragma unroll
      for (int ks = 0; ks < 4; ++ks) {
        const int chunk = (((ks * 2 + hi) ^ (arow & 7) ^ r2) & 7) * 16;
        af[ks] = *reinterpret_cast<const int32x4*>(&sAc[arow * BKI + chunk]);
      }

      // staging for tile t+1: 2 calls/phase (A in q0-1, B in q2-3; the
      // measured-best R12 spread). Loads stay in flight across barriers.
      if (pre) {
        if (q < 2) {
#pragma unroll
          for (int j = 0; j < 2; ++j) {
            const int part = q * 2 + j;
            load16_lds(Ag + gkn + (size_t)(part * 8) * Kb + swzj[part],
                       &sA[nxt][(wave * 32 + part * 8) * BKI]);
          }
        } else {
#pragma unroll
          for (int j = 0; j < 2; ++j) {
            const int part = (q - 2) * 2 + j;
            load16_lds(Bg + gkn + (size_t)(part * 8) * Kb + swzj[part],
                       &sB[nxt][(wave * 32 + part * 8) * BKI]);
          }
        }
      }

      __builtin_amdgcn_s_barrier();  // raw: next-tile loads stay in flight
      __builtin_amdgcn_s_setprio(1);
#pragma unroll
      for (int ks = 0; ks < 4; ++ks)
#pragma unroll
        for (int ni = 0; ni < 2; ++ni)
          acc[q][ni] = __builtin_amdgcn_mfma_scale_f32_32x32x64_f8f6f4(
              mk8(af[ks]), mk8(bfv[ni * 4 + ks]), acc[q][ni],
              4, 4,                 // cbsz=FP4(A), blgp=FP4(B)
              0, SCALE_ONE,         // opsel_a, scale_a = 1.0
              0, SCALE_ONE);        // opsel_b, scale_b = 1.0
      __builtin_amdgcn_s_setprio(0);
      __builtin_amdgcn_s_barrier();
    }
  }

  // ---- column stats: C/D 32x32 layout col=lane31, row=(r&3)+8(r>>2)+4hi --
#pragma unroll
  for (int ni = 0; ni < 2; ++ni) {
    const int col = colBlock + wn + ni * 32 + lane31;
    float s = 0.f, sq = 0.f;
#pragma unroll
    for (int mi = 0; mi < 4; ++mi)
#pragma unroll
      for (int r = 0; r < 16; ++r) {
        const float fv = acc[mi][ni][r];
        s += fv;
        sq += fv * fv;
      }
    // lanes l and l^32 hold the same column (different row halves)
    s  += __shfl_xor(s, 32);
    sq += __shfl_xor(sq, 32);
    if (hi == 0) {
      atomicAdd(&colSum[col], s);
      atomicAdd(&colSq[col], sq);
    }
  }

  // prefetch gamma/beta for the epilogue (latency hides under the barrier)
  float gmv = 0.f, btv = 0.f;
  if (tid < BN) {
    gmv = gamma[colBlock + tid];
    btv = beta[colBlock + tid];
  }

  // ---- per-panel grid barrier (no HW fences; R11-proven) ------------------
  // Panel p's columns touched only by its own nby row-blocks. All 256
  // blocks co-resident (128KiB LDS -> 1 block/CU x 256 CUs): no deadlock.
  __syncthreads();  // drains vmcnt: this block's stat atomics done at L3
  if (tid == 0) {
    int* bar = barriers + panel * BAR_STRIDE;
    __hip_atomic_fetch_add(bar, 1, __ATOMIC_RELAXED,
                           __HIP_MEMORY_SCOPE_AGENT);
    while (__hip_atomic_load(bar, __ATOMIC_RELAXED,
                             __HIP_MEMORY_SCOPE_AGENT) < nby) {
      __builtin_amdgcn_s_sleep(8);
    }
    asm volatile("" ::: "memory");  // compiler-only ordering; no L2 inv
  }
  __syncthreads();

  // ---- stage per-column (scale, shift) in LDS (aliased on sA) -------------
  float2* sSC = reinterpret_cast<float2*>(&sA[0][0]);  // 256 pairs = 2 KiB
  if (tid < BN) {
    const int col = colBlock + tid;
    const float s  = __hip_atomic_load(&colSum[col], __ATOMIC_RELAXED,
                                       __HIP_MEMORY_SCOPE_AGENT);
    const float sq = __hip_atomic_load(&colSq[col], __ATOMIC_RELAXED,
                                       __HIP_MEMORY_SCOPE_AGENT);
    const float invM = 1.0f / (float)M;
    const float mu  = s * invM;
    const float var = sq * invM - mu * mu;
    const float sc  = gmv * rsqrtf(var + EPS_BN);
    const float sh  = btv - mu * sc;
    sSC[tid] = make_float2(sc, sh);
  }
  __syncthreads();

  // ---- normalize in registers, write final f32 ----------------------------
#pragma unroll
  for (int ni = 0; ni < 2; ++ni) {
    const int lc  = wn + ni * 32 + lane31;  // block-local column
    const float2 ss = sSC[lc];
    const int col = colBlock + lc;
#pragma unroll
    for (int mi = 0; mi < 4; ++mi) {
#pragma unroll
      for (int r = 0; r < 16; ++r) {
        const int row = rowBlock + wm + mi * 32 + (r & 3) + 8 * (r >> 2) +
                        4 * hi;
        C[(size_t)row * N + col] = acc[mi][ni][r] * ss.x + ss.y;
      }
    }
  }
}

// ---------------------------------------------------------------------------
extern "C" void kernel_launch(void* const* d_in, const int* in_sizes, int n_in,
                              void* d_out, int out_size, void* d_ws,
                              size_t ws_size, hipStream_t stream) {
  const float* x     = (const float*)d_in[0];
  const float* w     = (const float*)d_in[1];
  const float* gamma = (const float*)d_in[2];
  const float* beta  = (const float*)d_in[3];
  float* C = (float*)d_out;

  const int N = in_sizes[2];      // OUT
  const int K = in_sizes[1] / N;  // IN
  const int M = in_sizes[0] / K;  // batch

  // workspace: [A fp4 M*K/2][B fp4 N*K/2][colSum N][colSq N][barriers]
  char* ws = (char*)d_ws;
  char* Abin = ws;
  char* Bbin = ws + (size_t)M * K / 2;
  float* stats = (float*)(ws + (size_t)M * K / 2 + (size_t)N * K / 2);
  float* colSum = stats;
  float* colSq  = stats + N;
  int* barriers = (int*)(stats + 2 * N);

  {
    int nx8 = (M * K) / 8;
    int ntot8 = (M * K + N * K) / 8;
    // zero colSum, colSq, and the 16 padded barrier counters
    binarize_kernel<<<(ntot8 + 255) / 256, 256, 0, stream>>>(
        x, w, (unsigned*)Abin, (unsigned*)Bbin, stats, nx8, ntot8,
        2 * N + 16 * BAR_STRIDE);
  }

  {
    const int nTiles = (M / BM) * (N / BN);  // 256 = 256 CUs x 1 block
    gemm_bn_kernel<<<nTiles, 512, 0, stream>>>(Abin, Bbin, C, colSum, colSq,
                                               barriers, gamma, beta, M, N, K);
  }
}